// Round 5
// baseline (2243.322 us; speedup 1.0000x reference)
//
#include <hip/hip_runtime.h>
#include <hip/hip_bf16.h>

#define EPS 1e-5f
#define SLOPE 0.01f

typedef short bf16x8 __attribute__((ext_vector_type(8)));  // 8 bf16 in 4 VGPRs
typedef float f32x4  __attribute__((ext_vector_type(4)));

__device__ inline unsigned short f2bf(float f) {
    union { __hip_bfloat16 h; unsigned short u; } cv;
    cv.h = __float2bfloat16(f);
    return cv.u;
}
__device__ inline bf16x8 pack8(float4 lo, float4 hi) {
    bf16x8 v;
    v[0] = (short)f2bf(lo.x); v[1] = (short)f2bf(lo.y);
    v[2] = (short)f2bf(lo.z); v[3] = (short)f2bf(lo.w);
    v[4] = (short)f2bf(hi.x); v[5] = (short)f2bf(hi.y);
    v[6] = (short)f2bf(hi.z); v[7] = (short)f2bf(hi.w);
    return v;
}

// ---------------------------------------------------------------------------
// Weight pre-transpose: Wt[k][cout][cin] = bf16(W[k][cin][cout]).
// ---------------------------------------------------------------------------
__global__ __launch_bounds__(256) void wtrans(
    const float* __restrict__ W, unsigned short* __restrict__ Wt, int Cin)
{
    __shared__ float tl[64][65];
    const int k  = blockIdx.y;
    const int ib = blockIdx.x << 6;
    const int t  = threadIdx.x;
    for (int it = 0; it < 16; ++it) {
        int idx = it * 256 + t, r = idx >> 6, c = idx & 63;
        tl[r][c] = W[(size_t)k * Cin * 64 + (size_t)(ib + r) * 64 + c];
    }
    __syncthreads();
    for (int it = 0; it < 16; ++it) {
        int idx = it * 256 + t, r = idx >> 6, c = idx & 63;
        Wt[(size_t)k * 64 * Cin + (size_t)r * Cin + ib + c] = f2bf(tl[c][r]);
    }
}

// ---------------------------------------------------------------------------
// CSR build: histogram / scan / fill
// Coarse convs keyed by (dstTile, k); payload = src | dstLocal<<18.
// Up conv keyed by fine row; payload = coarse | k<<16.
// ---------------------------------------------------------------------------
__global__ void hist_coarse(const int* __restrict__ dst, int E, int* __restrict__ cnt) {
    int e = blockIdx.x * 256 + threadIdx.x, k = blockIdx.y;
    if (e < E) atomicAdd(&cnt[(dst[(size_t)k * E + e] >> 6) * 27 + k], 1);
}
__global__ void fill_coarse(const int* __restrict__ src, const int* __restrict__ dst,
                            int E, int* __restrict__ cur, int* __restrict__ elist) {
    int e = blockIdx.x * 256 + threadIdx.x, k = blockIdx.y;
    if (e < E) {
        int d = dst[(size_t)k * E + e];
        int pos = atomicAdd(&cur[(d >> 6) * 27 + k], 1);
        elist[pos] = src[(size_t)k * E + e] | ((d & 63) << 18);
    }
}
__global__ void hist_up(const int* __restrict__ fine, int E, int* __restrict__ cnt) {
    int e = blockIdx.x * 256 + threadIdx.x, k = blockIdx.y;
    if (e < E) atomicAdd(&cnt[fine[(size_t)k * E + e]], 1);
}
__global__ void fill_up(const int* __restrict__ fine, const int* __restrict__ coarse,
                        int E, int* __restrict__ cur, int* __restrict__ elist) {
    int e = blockIdx.x * 256 + threadIdx.x, k = blockIdx.y;
    if (e < E) {
        int f = fine[(size_t)k * E + e];
        int pos = atomicAdd(&cur[f], 1);
        elist[pos] = coarse[(size_t)k * E + e] | (k << 16);
    }
}

// Three independent exclusive scans (one per block).
__global__ __launch_bounds__(256) void scan3(
    int* c0, int* p0, int* u0, int n0,
    int* c1, int* p1, int* u1, int n1,
    int* c2, int* p2, int* u2, int n2)
{
    int *cnt, *ptr, *cur; int n;
    if (blockIdx.x == 0)      { cnt = c0; ptr = p0; cur = u0; n = n0; }
    else if (blockIdx.x == 1) { cnt = c1; ptr = p1; cur = u1; n = n1; }
    else                      { cnt = c2; ptr = p2; cur = u2; n = n2; }
    __shared__ int ls[256];
    __shared__ int base_s;
    const int t = threadIdx.x;
    if (t == 0) base_s = 0;
    __syncthreads();
    for (int chunk = 0; chunk * 1024 < n; ++chunk) {
        int i0 = chunk * 1024 + t * 4;
        int v0 = (i0 + 0 < n) ? cnt[i0 + 0] : 0;
        int v1 = (i0 + 1 < n) ? cnt[i0 + 1] : 0;
        int v2 = (i0 + 2 < n) ? cnt[i0 + 2] : 0;
        int v3 = (i0 + 3 < n) ? cnt[i0 + 3] : 0;
        int tot = v0 + v1 + v2 + v3;
        ls[t] = tot; __syncthreads();
        for (int off = 1; off < 256; off <<= 1) {
            int a = (t >= off) ? ls[t - off] : 0;
            __syncthreads();
            ls[t] += a; __syncthreads();
        }
        int incl = ls[t], bt = ls[255];
        int excl = incl - tot + base_s;
        if (i0 + 0 < n) { ptr[i0 + 0] = excl;                cur[i0 + 0] = excl; }
        if (i0 + 1 < n) { ptr[i0 + 1] = excl + v0;           cur[i0 + 1] = excl + v0; }
        if (i0 + 2 < n) { ptr[i0 + 2] = excl + v0 + v1;      cur[i0 + 2] = excl + v0 + v1; }
        if (i0 + 3 < n) { ptr[i0 + 3] = excl + v0 + v1 + v2; cur[i0 + 3] = excl + v0 + v1 + v2; }
        __syncthreads();
        if (t == 0) base_s += bt;
        __syncthreads();
    }
}

// 3-pass scan for the fine-row CSR (n = Nf)
__global__ __launch_bounds__(256) void scan_p1(const int* __restrict__ cnt,
                                               int* __restrict__ ptr, int n,
                                               int* __restrict__ tmp) {
    __shared__ int ls[256];
    const int t = threadIdx.x;
    int i0 = blockIdx.x * 1024 + t * 4;
    int v0 = (i0 + 0 < n) ? cnt[i0 + 0] : 0;
    int v1 = (i0 + 1 < n) ? cnt[i0 + 1] : 0;
    int v2 = (i0 + 2 < n) ? cnt[i0 + 2] : 0;
    int v3 = (i0 + 3 < n) ? cnt[i0 + 3] : 0;
    int tot = v0 + v1 + v2 + v3;
    ls[t] = tot; __syncthreads();
    for (int off = 1; off < 256; off <<= 1) {
        int a = (t >= off) ? ls[t - off] : 0;
        __syncthreads();
        ls[t] += a; __syncthreads();
    }
    int excl = ls[t] - tot;
    if (i0 + 0 < n) ptr[i0 + 0] = excl;
    if (i0 + 1 < n) ptr[i0 + 1] = excl + v0;
    if (i0 + 2 < n) ptr[i0 + 2] = excl + v0 + v1;
    if (i0 + 3 < n) ptr[i0 + 3] = excl + v0 + v1 + v2;
    if (t == 255) tmp[blockIdx.x] = ls[255];
}
__global__ __launch_bounds__(256) void scan_p2(int* __restrict__ tmp, int n) {
    __shared__ int ls[256];
    const int t = threadIdx.x;
    int v = (t < n) ? tmp[t] : 0;
    ls[t] = v; __syncthreads();
    for (int off = 1; off < 256; off <<= 1) {
        int a = (t >= off) ? ls[t - off] : 0;
        __syncthreads();
        ls[t] += a; __syncthreads();
    }
    if (t < n) tmp[t] = ls[t] - v;
}
__global__ __launch_bounds__(256) void scan_p3(int* __restrict__ ptr, int* __restrict__ cur,
                                               int n, const int* __restrict__ tmp) {
    int i0 = blockIdx.x * 1024 + threadIdx.x * 4;
    int b = tmp[blockIdx.x];
    #pragma unroll
    for (int j = 0; j < 4; ++j)
        if (i0 + j < n) { int v = ptr[i0 + j] + b; ptr[i0 + j] = v; cur[i0 + j] = v; }
}

// ---------------------------------------------------------------------------
// Chunk descriptors: one per (16-edge chunk, 64-cin half).
// desc.x = absolute elist offset; desc.y = k | cnt<<8 | half<<16.
// ---------------------------------------------------------------------------
__global__ __launch_bounds__(256) void chunk_count(
    const int* __restrict__ segCnt, int Tc, int halves, int* __restrict__ out)
{
    int tile = blockIdx.x * 256 + threadIdx.x;
    if (tile < Tc) {
        int s = 0;
        for (int k = 0; k < 27; ++k) s += (segCnt[tile * 27 + k] + 15) >> 4;
        out[tile] = s * halves;
    }
}
__global__ __launch_bounds__(256) void desc_fill(
    const int* __restrict__ segPtr, const int* __restrict__ segCnt, int Tc,
    int halves, const int* __restrict__ chPtr, int2* __restrict__ desc)
{
    int tile = blockIdx.x * 256 + threadIdx.x;
    if (tile >= Tc) return;
    int w = chPtr[tile];
    for (int k = 0; k < 27; ++k) {
        int len = segCnt[tile * 27 + k], base = segPtr[tile * 27 + k];
        for (int ic = 0; ic * 16 < len; ++ic) {
            int cnt = min(16, len - ic * 16);
            for (int h = 0; h < halves; ++h)
                desc[w++] = make_int2(base + ic * 16, k | (cnt << 8) | (h << 16));
        }
    }
}

// ---------------------------------------------------------------------------
// MFMA gather-GEMM conv, software-pipelined (4-phase rotation per wave):
//   desc(i+12) | ev(i+8) | x+B gather(i+4) | compute(i)
// Every load issued >=1 stage before its consumption -> each wave keeps a full
// 16-row gather (~64 cache lines) in flight continuously (the round-4 kernel
// exposed every gather's latency serially -> VALUBusy 1.8%).
// Block per 64-row dst tile, 4 waves; items strided by 4 across waves.
// CIN=128 handled as two 64-cin halves (uniform KS=2 shape; partial sums of
// the two halves meet in the LDS atomicAdd). Two conv problems fused per
// dispatch via blockIdx.y. 2 block barriers total. BN stats fused.
// ---------------------------------------------------------------------------
__global__ __launch_bounds__(256, 3) void conv_mfma3(
    const float* __restrict__ xA, const unsigned short* __restrict__ WtA,
    const int2* __restrict__ descA, const int* __restrict__ chPtrA,
    const int* __restrict__ chCntA, const int* __restrict__ elA,
    float* __restrict__ outA, float* __restrict__ stA, int cinA,
    const float* __restrict__ xB, const unsigned short* __restrict__ WtB,
    const int2* __restrict__ descB, const int* __restrict__ chPtrB,
    const int* __restrict__ chCntB, const int* __restrict__ elB,
    float* __restrict__ outB, float* __restrict__ stB, int cinB, int Nc)
{
    __shared__ float accs[64 * 64];
    __shared__ float sred[256], qred[256];

    const float* x; const unsigned short* Wt; const int2* desc;
    const int* chPtr; const int* chCnt; const int* elist;
    float* out; float* st; int cin;
    if (blockIdx.y == 0) {
        x = xA; Wt = WtA; desc = descA; chPtr = chPtrA; chCnt = chCntA;
        elist = elA; out = outA; st = stA; cin = cinA;
    } else {
        x = xB; Wt = WtB; desc = descB; chPtr = chPtrB; chCnt = chCntB;
        elist = elB; out = outB; st = stB; cin = cinB;
    }

    const int t    = threadIdx.x;
    const int tile = blockIdx.x, tb = tile << 6;
    const int wv   = t >> 6, lane = t & 63;
    const int nidx = lane & 15, quad = lane >> 4;

    for (int i = t; i < 4096; i += 256) accs[i] = 0.f;
    __syncthreads();

    const int cb = chPtr[tile];
    const int ni = chCnt[tile];

    auto descL = [&](int idx) -> int2 {
        return (idx < ni) ? desc[cb + idx] : make_int2(0, 0);
    };
    auto evL = [&](int2 d) -> int {
        const int cnt = (d.y >> 8) & 31;
        return (nidx < cnt) ? elist[d.x + nidx] : 0;
    };
    auto gatherL = [&](int2 d, int ev, float4 (&r)[4], bf16x8 (&b)[4][2]) {
        const int k = d.y & 31, cnt = (d.y >> 8) & 31;
        const int cinOff = ((d.y >> 16) & 1) << 6;
        if (nidx < cnt) {
            const float* xr = x + (size_t)(ev & 0x3FFFF) * cin + cinOff + quad * 8;
            r[0] = *(const float4*)(xr);
            r[1] = *(const float4*)(xr + 4);
            r[2] = *(const float4*)(xr + 32);
            r[3] = *(const float4*)(xr + 36);
        } else {
            float4 z = make_float4(0.f, 0.f, 0.f, 0.f);
            r[0] = z; r[1] = z; r[2] = z; r[3] = z;
        }
        const unsigned short* Wk = Wt + ((size_t)k * 64 + nidx) * cin + cinOff + quad * 8;
        #pragma unroll
        for (int g = 0; g < 4; ++g) {
            const unsigned short* Wr = Wk + (size_t)(g * 16) * cin;
            b[g][0] = *(const bf16x8*)(Wr);
            b[g][1] = *(const bf16x8*)(Wr + 32);
        }
    };
    auto computeL = [&](int ev, float4 (&r)[4], bf16x8 (&b)[4][2]) {
        const bf16x8 a0 = pack8(r[0], r[1]);
        const bf16x8 a1 = pack8(r[2], r[3]);
        f32x4 acc[4];
        #pragma unroll
        for (int g = 0; g < 4; ++g) acc[g] = (f32x4){0.f, 0.f, 0.f, 0.f};
        #pragma unroll
        for (int g = 0; g < 4; ++g) {
            acc[g] = __builtin_amdgcn_mfma_f32_16x16x32_bf16(a0, b[g][0], acc[g], 0, 0, 0);
            acc[g] = __builtin_amdgcn_mfma_f32_16x16x32_bf16(a1, b[g][1], acc[g], 0, 0, 0);
        }
        // C layout: row(edge) = quad*4+r4, col = nidx. Edge e's ev is in lane e.
        #pragma unroll
        for (int r4 = 0; r4 < 4; ++r4) {
            const int e   = quad * 4 + r4;
            const int evE = __shfl(ev, e);
            const int dl  = (evE >> 18) & 63;   // padded edges add 0.0
            #pragma unroll
            for (int g = 0; g < 4; ++g)
                atomicAdd(&accs[dl * 64 + g * 16 + nidx], acc[g][r4]);
        }
    };

    // ---- pipeline (items wv, wv+4, wv+8, ...) ----
    int2 d0, d1, d2, d3;
    int  ev0, ev1, ev2, ev3;
    float4 R0[4], R1[4];
    bf16x8 B0[4][2], B1[4][2];

    int i = wv;
    d0 = descL(i);
    ev0 = evL(d0);
    d1 = descL(i + 4);
    gatherL(d0, ev0, R0, B0);
    ev1 = evL(d1);
    d2 = descL(i + 8);

    for (;;) {
        if (i >= ni) break;                      // P0: compute item i (R0)
        gatherL(d1, ev1, R1, B1);
        ev2 = evL(d2);
        d3 = descL(i + 12);
        computeL(ev0, R0, B0);
        i += 4;
        if (i >= ni) break;                      // P1: compute (R1)
        gatherL(d2, ev2, R0, B0);
        ev3 = evL(d3);
        d0 = descL(i + 12);
        computeL(ev1, R1, B1);
        i += 4;
        if (i >= ni) break;                      // P2: compute (R0)
        gatherL(d3, ev3, R1, B1);
        ev0 = evL(d0);
        d1 = descL(i + 12);
        computeL(ev2, R0, B0);
        i += 4;
        if (i >= ni) break;                      // P3: compute (R1)
        gatherL(d0, ev0, R0, B0);
        ev1 = evL(d1);
        d2 = descL(i + 12);
        computeL(ev3, R1, B1);
        i += 4;
    }
    __syncthreads();

    // fused per-channel BN stats (rows beyond Nc are zero)
    {
        const int c = t & 63, rg = t >> 6;
        float s = 0.f, qq = 0.f;
        for (int r = rg * 16; r < rg * 16 + 16; ++r) {
            const float v = accs[r * 64 + c];
            s += v; qq = fmaf(v, v, qq);
        }
        sred[t] = s; qred[t] = qq;
    }
    __syncthreads();
    if (t < 64) {
        float s  = sred[t] + sred[64 + t] + sred[128 + t] + sred[192 + t];
        float qq = qred[t] + qred[64 + t] + qred[128 + t] + qred[192 + t];
        atomicAdd(&st[t], s);
        atomicAdd(&st[64 + t], qq);
    }
    // write rows once
    {
        const int r = t >> 2, cb4 = (t & 3) << 4;
        const int row = tb + r;
        if (row < Nc) {
            #pragma unroll
            for (int v = 0; v < 4; ++v)
                *(float4*)&out[(size_t)row * 64 + cb4 + v * 4] =
                    *(float4*)&accs[r * 64 + cb4 + v * 4];
        }
    }
}

// ---------------------------------------------------------------------------
// Cout=1 conv, same descriptor pipeline (uses desc_g half-0 entries, stride 2).
// Lane (nidx=edge, quad=16-ch group): partial dot; reduce quads via shfl_xor;
// LDS atomic into 64-float tile accumulator. Fused scalar BN stats.
// ---------------------------------------------------------------------------
__global__ __launch_bounds__(256) void conv_sum_p(
    const float* __restrict__ s, const float* __restrict__ Wsum,
    const int2* __restrict__ desc, const int* __restrict__ chPtr,
    const int* __restrict__ chCnt, const int* __restrict__ elist,
    float* __restrict__ D, float* __restrict__ st, int Nc)
{
    __shared__ float acc1[64];
    const int t = threadIdx.x, wv = t >> 6, lane = t & 63;
    const int nidx = lane & 15, quad = lane >> 4;
    const int tile = blockIdx.x, tb = tile << 6;
    if (t < 64) acc1[t] = 0.f;
    __syncthreads();

    const int cb  = chPtr[tile];
    const int nch = chCnt[tile] >> 1;      // halves=2 in desc_g; use h=0 entries

    auto descL = [&](int m) -> int2 {
        return (m < nch) ? desc[cb + 2 * m] : make_int2(0, 0);
    };
    auto evL = [&](int2 d) -> int {
        const int c = (d.y >> 8) & 31;
        return (nidx < c) ? elist[d.x + nidx] : 0;
    };
    auto gat = [&](int2 d, int ev, float4 (&r)[4]) {
        const int c = (d.y >> 8) & 31;
        if (nidx < c) {
            const float4* sr = (const float4*)(s + (size_t)(ev & 0x3FFFF) * 64 + quad * 16);
            r[0] = sr[0]; r[1] = sr[1]; r[2] = sr[2]; r[3] = sr[3];
        } else {
            float4 z = make_float4(0.f, 0.f, 0.f, 0.f);
            r[0] = z; r[1] = z; r[2] = z; r[3] = z;
        }
    };
    auto comp = [&](int2 d, int ev, float4 (&r)[4]) {
        const int k = d.y & 31;
        const float4* wr = (const float4*)(Wsum + k * 64 + quad * 16);
        float p = 0.f;
        #pragma unroll
        for (int u = 0; u < 4; ++u) {
            const float4 w4 = wr[u];
            p = fmaf(r[u].x, w4.x, p); p = fmaf(r[u].y, w4.y, p);
            p = fmaf(r[u].z, w4.z, p); p = fmaf(r[u].w, w4.w, p);
        }
        p += __shfl_xor(p, 16);
        p += __shfl_xor(p, 32);
        if (quad == 0) atomicAdd(&acc1[(ev >> 18) & 63], p);
    };

    int2 d0, d1, d2, d3;
    int  ev0, ev1, ev2, ev3;
    float4 R0[4], R1[4];

    int m = wv;
    d0 = descL(m);
    ev0 = evL(d0);
    d1 = descL(m + 4);
    gat(d0, ev0, R0);
    ev1 = evL(d1);
    d2 = descL(m + 8);

    for (;;) {
        if (m >= nch) break;
        gat(d1, ev1, R1);
        ev2 = evL(d2);
        d3 = descL(m + 12);
        comp(d0, ev0, R0);
        m += 4;
        if (m >= nch) break;
        gat(d2, ev2, R0);
        ev3 = evL(d3);
        d0 = descL(m + 12);
        comp(d1, ev1, R1);
        m += 4;
        if (m >= nch) break;
        gat(d3, ev3, R1);
        ev0 = evL(d0);
        d1 = descL(m + 12);
        comp(d2, ev2, R0);
        m += 4;
        if (m >= nch) break;
        gat(d0, ev0, R0);
        ev1 = evL(d1);
        d2 = descL(m + 12);
        comp(d3, ev3, R1);
        m += 4;
    }
    __syncthreads();
    if (t < 64) {
        float v = acc1[t];
        if (tb + t < Nc) D[tb + t] = v;
        float p = v, qq = v * v;
        for (int off = 32; off; off >>= 1) {
            p  += __shfl_down(p, off);
            qq += __shfl_down(qq, off);
        }
        if (t == 0) { atomicAdd(&st[0], p); atomicAdd(&st[1], qq); }
    }
}

// ---------------------------------------------------------------------------
// Cin=1 up-conv, gather form over fine rows. Wave per row; fused stats.
// ---------------------------------------------------------------------------
__global__ __launch_bounds__(256) void conv_up_t(
    const float* __restrict__ s1, const float* __restrict__ Wup,
    const int* __restrict__ rowPtr, const int* __restrict__ rowCnt,
    const int* __restrict__ elist, float* __restrict__ out,
    float* __restrict__ st, int Nf)
{
    __shared__ float WL[27 * 64];
    __shared__ float sred[256], qred[256];
    const int t = threadIdx.x, wv = t >> 6, c = t & 63;
    for (int i = t; i < 27 * 64; i += 256) WL[i] = Wup[i];
    __syncthreads();
    float ssum = 0.f, ssq = 0.f;
    for (int row = blockIdx.x * 4 + wv; row < Nf; row += gridDim.x * 4) {
        int b = rowPtr[row], len = rowCnt[row];
        float acc = 0.f;
        for (int j = 0; j < len; ++j) {
            int ev = elist[b + j];
            float sv = s1[ev & 0xFFFF];
            acc = fmaf(sv, WL[(ev >> 16) * 64 + c], acc);
        }
        out[(size_t)row * 64 + c] = acc;
        ssum += acc; ssq = fmaf(acc, acc, ssq);
    }
    sred[t] = ssum; qred[t] = ssq;
    __syncthreads();
    if (t < 64) {
        float s = sred[t] + sred[64 + t] + sred[128 + t] + sred[192 + t];
        float q = qred[t] + qred[64 + t] + qred[128 + t] + qred[192 + t];
        atomicAdd(&st[t], s);
        atomicAdd(&st[64 + t], q);
    }
}

// ---------------------------------------------------------------------------
// BN apply (64 channels), in-place. ACT 0 = LeakyReLU, 1 = sigmoid.
// ---------------------------------------------------------------------------
template<int ACT>
__global__ __launch_bounds__(256) void bn_f32(
    float* __restrict__ xx, const float* __restrict__ st, int N, float invN,
    const float* __restrict__ gam, const float* __restrict__ bet,
    const float* __restrict__ add)
{
    __shared__ float sc[64], sh[64];
    if (threadIdx.x < 64) {
        int c = threadIdx.x;
        float m = st[c] * invN;
        float v = st[64 + c] * invN - m * m;
        float s = rsqrtf(v + EPS) * gam[c];
        sc[c] = s; sh[c] = bet[c] - m * s;
    }
    __syncthreads();
    size_t n = (size_t)N * 64;
    for (size_t i = (size_t)blockIdx.x * 256 + threadIdx.x; i < n;
         i += (size_t)gridDim.x * 256) {
        int c = (int)(i & 63);
        float y = fmaf(xx[i], sc[c], sh[c]);
        if (ACT == 0) y = (y >= 0.f) ? y : SLOPE * y;
        else          y = 1.f / (1.f + __expf(-y));
        if (add) y += add[i];
        xx[i] = y;
    }
}

__global__ __launch_bounds__(256) void bn1(
    float* __restrict__ x, const float* __restrict__ st, int N, float invN,
    const float* __restrict__ gam, const float* __restrict__ bet)
{
    const float m  = st[0] * invN;
    const float v  = st[1] * invN - m * m;
    const float s  = rsqrtf(v + EPS) * gam[0];
    const float sh = bet[0] - m * s;
    for (int i = blockIdx.x * 256 + threadIdx.x; i < N; i += gridDim.x * 256) {
        float y = fmaf(x[i], s, sh);
        x[i] = (y >= 0.f) ? y : SLOPE * y;
    }
}

// ---------------------------------------------------------------------------
extern "C" void kernel_launch(void* const* d_in, const int* in_sizes, int n_in,
                              void* d_out, int out_size, void* d_ws, size_t ws_size,
                              hipStream_t stream)
{
    const float* gate     = (const float*)d_in[0];
    const float* shortcut = (const float*)d_in[1];
    const int*   src_down = (const int*)d_in[2];
    const int*   dst_down = (const int*)d_in[3];
    const int*   src_g    = (const int*)d_in[4];
    const int*   dst_g    = (const int*)d_in[5];
    const float* W_sc     = (const float*)d_in[6];
    const float* W_g      = (const float*)d_in[8];
    const float* W_gu     = (const float*)d_in[10];
    const float* W_sum    = (const float*)d_in[12];
    const float* W_up     = (const float*)d_in[13];
    const float* gam_sc   = (const float*)d_in[15];
    const float* bet_sc   = (const float*)d_in[16];
    const float* gam_g    = (const float*)d_in[17];
    const float* bet_g    = (const float*)d_in[18];
    const float* gam_gu   = (const float*)d_in[19];
    const float* bet_gu   = (const float*)d_in[20];
    const float* gam_sum  = (const float*)d_in[21];
    const float* bet_sum  = (const float*)d_in[22];
    const float* gam_up   = (const float*)d_in[23];
    const float* bet_up   = (const float*)d_in[24];

    const int K   = 27;
    const int Nc  = in_sizes[0] / 128;   // 60000
    const int Nf  = in_sizes[1] / 64;    // 200000
    const int Ekd = in_sizes[2] / K;     // 40000
    const int Ekg = in_sizes[4] / K;     // 25000
    const int Tc  = (Nc + 63) >> 6;      // coarse tiles
    const int NBc = Tc * 27;             // coarse bins

    const int descCap_sc = (K * Ekd) / 16 + NBc + 64;
    const int descCap_g  = 2 * ((K * Ekg) / 16 + NBc) + 64;
    const int descCap_gT = (K * Ekg) / 16 + NBc + 64;

    // ---- workspace layout ----
    char* p = (char*)d_ws;
    auto alloc = [&](size_t bytes) -> void* {
        void* r = (void*)p; p += (bytes + 255) & ~(size_t)255; return r;
    };
    float* ST      = (float*)alloc(640 * 4);            // memset region start
    int*   cnt_sc  = (int*)alloc((size_t)NBc * 4);
    int*   cnt_g   = (int*)alloc((size_t)NBc * 4);
    int*   cnt_gT  = (int*)alloc((size_t)NBc * 4);
    int*   cnt_up  = (int*)alloc((size_t)Nf * 4);       // memset region end
    size_t zspan   = (size_t)(p - (char*)ST);
    int*   ptr_sc  = (int*)alloc((size_t)NBc * 4);
    int*   cur_sc  = (int*)alloc((size_t)NBc * 4);
    int*   ptr_g   = (int*)alloc((size_t)NBc * 4);
    int*   cur_g   = (int*)alloc((size_t)NBc * 4);
    int*   ptr_gT  = (int*)alloc((size_t)NBc * 4);
    int*   cur_gT  = (int*)alloc((size_t)NBc * 4);
    int*   ptr_up  = (int*)alloc((size_t)Nf * 4);
    int*   cur_up  = (int*)alloc((size_t)Nf * 4);
    int*   stmp    = (int*)alloc(256 * 4);
    int*   chCnt_sc = (int*)alloc((size_t)Tc * 4);
    int*   chCnt_g  = (int*)alloc((size_t)Tc * 4);
    int*   chCnt_gT = (int*)alloc((size_t)Tc * 4);
    int*   chPtr_sc = (int*)alloc((size_t)Tc * 4);
    int*   chPtr_g  = (int*)alloc((size_t)Tc * 4);
    int*   chPtr_gT = (int*)alloc((size_t)Tc * 4);
    int2*  desc_sc  = (int2*)alloc((size_t)descCap_sc * 8);
    int2*  desc_g   = (int2*)alloc((size_t)descCap_g * 8);
    int2*  desc_gT  = (int2*)alloc((size_t)descCap_gT * 8);
    int*   el_sc   = (int*)alloc((size_t)K * Ekd * 4);
    int*   el_g    = (int*)alloc((size_t)K * Ekg * 4);
    int*   el_gT   = (int*)alloc((size_t)K * Ekg * 4);
    int*   el_up   = (int*)alloc((size_t)K * Ekd * 4);
    unsigned short* Wt_sc = (unsigned short*)alloc((size_t)K * 64 * 64 * 2);
    unsigned short* Wt_g  = (unsigned short*)alloc((size_t)K * 128 * 64 * 2);
    unsigned short* Wt_gu = (unsigned short*)alloc((size_t)K * 64 * 64 * 2);
    float* Ab = (float*)alloc((size_t)Nc * 64 * 4);
    float* Bb = (float*)alloc((size_t)Nc * 64 * 4);
    float* Cb = (float*)alloc((size_t)Nc * 64 * 4);
    float* Db = (float*)alloc((size_t)Nc * 4);
    float* outF = (float*)d_out;

    hipMemsetAsync(ST, 0, zspan, stream);

    const dim3 blk(256);

    // weights -> bf16 transposed
    wtrans<<<dim3(1, K), blk, 0, stream>>>(W_sc, Wt_sc, 64);
    wtrans<<<dim3(2, K), blk, 0, stream>>>(W_g,  Wt_g,  128);
    wtrans<<<dim3(1, K), blk, 0, stream>>>(W_gu, Wt_gu, 64);

    // CSR builds
    const dim3 gEkd((Ekd + 255) / 256, K), gEkg((Ekg + 255) / 256, K);
    hist_coarse<<<gEkd, blk, 0, stream>>>(dst_down, Ekd, cnt_sc);
    hist_coarse<<<gEkg, blk, 0, stream>>>(dst_g,    Ekg, cnt_g);
    hist_coarse<<<gEkg, blk, 0, stream>>>(src_g,    Ekg, cnt_gT);
    hist_up<<<gEkd, blk, 0, stream>>>(src_down, Ekd, cnt_up);
    scan3<<<3, blk, 0, stream>>>(cnt_sc, ptr_sc, cur_sc, NBc,
                                 cnt_g,  ptr_g,  cur_g,  NBc,
                                 cnt_gT, ptr_gT, cur_gT, NBc);
    const int nCh = (Nf + 1023) / 1024;
    scan_p1<<<nCh, blk, 0, stream>>>(cnt_up, ptr_up, Nf, stmp);
    scan_p2<<<1, blk, 0, stream>>>(stmp, nCh);
    scan_p3<<<nCh, blk, 0, stream>>>(ptr_up, cur_up, Nf, stmp);
    fill_coarse<<<gEkd, blk, 0, stream>>>(src_down, dst_down, Ekd, cur_sc, el_sc);
    fill_coarse<<<gEkg, blk, 0, stream>>>(src_g,    dst_g,    Ekg, cur_g,  el_g);
    fill_coarse<<<gEkg, blk, 0, stream>>>(dst_g,    src_g,    Ekg, cur_gT, el_gT);
    fill_up<<<gEkd, blk, 0, stream>>>(src_down, dst_down, Ekd, cur_up, el_up);

    // chunk descriptor lists
    const int gTc = (Tc + 255) / 256;
    chunk_count<<<gTc, blk, 0, stream>>>(cnt_sc, Tc, 1, chCnt_sc);
    chunk_count<<<gTc, blk, 0, stream>>>(cnt_g,  Tc, 2, chCnt_g);
    chunk_count<<<gTc, blk, 0, stream>>>(cnt_gT, Tc, 1, chCnt_gT);
    scan3<<<3, blk, 0, stream>>>(chCnt_sc, chPtr_sc, chPtr_sc, Tc,
                                 chCnt_g,  chPtr_g,  chPtr_g,  Tc,
                                 chCnt_gT, chPtr_gT, chPtr_gT, Tc);
    desc_fill<<<gTc, blk, 0, stream>>>(ptr_sc, cnt_sc, Tc, 1, chPtr_sc, desc_sc);
    desc_fill<<<gTc, blk, 0, stream>>>(ptr_g,  cnt_g,  Tc, 2, chPtr_g,  desc_g);
    desc_fill<<<gTc, blk, 0, stream>>>(ptr_gT, cnt_gT, Tc, 1, chPtr_gT, desc_gT);

    // theta = sconv(shortcut, W_sc)  ||  phi_raw = sconv(gate, W_g)   (fused)
    conv_mfma3<<<dim3(Tc, 2), blk, 0, stream>>>(
        shortcut, Wt_sc, desc_sc, chPtr_sc, chCnt_sc, el_sc, Ab, ST + 0,  64,
        gate,     Wt_g,  desc_g,  chPtr_g,  chCnt_g,  el_g,  Bb, ST + 128, 128, Nc);
    bn_f32<0><<<1024, blk, 0, stream>>>(Ab, ST + 0,   Nc, 1.f / Nc, gam_sc, bet_sc, nullptr);
    bn_f32<0><<<1024, blk, 0, stream>>>(Bb, ST + 128, Nc, 1.f / Nc, gam_g,  bet_g,  nullptr);
    // phi = sconv(phi, W_gu, transposed pairs)
    conv_mfma3<<<dim3(Tc, 1), blk, 0, stream>>>(
        Bb, Wt_gu, desc_gT, chPtr_gT, chCnt_gT, el_gT, Cb, ST + 256, 64,
        Bb, Wt_gu, desc_gT, chPtr_gT, chCnt_gT, el_gT, Cb, ST + 256, 64, Nc);
    // s = leaky(bn(C)) + theta
    bn_f32<0><<<1024, blk, 0, stream>>>(Cb, ST + 256, Nc, 1.f / Nc, gam_gu, bet_gu, Ab);
    // s1 = leaky(bn(sconv(s, W_sum)))
    conv_sum_p<<<Tc, blk, 0, stream>>>(Cb, W_sum, desc_g, chPtr_g, chCnt_g, el_g,
                                       Db, ST + 384, Nc);
    bn1<<<256, blk, 0, stream>>>(Db, ST + 384, Nc, 1.f / Nc, gam_sum, bet_sum);
    // out = sigmoid(bn(sconv(s1, W_up, inverse pairs)))
    conv_up_t<<<2048, blk, 0, stream>>>(Db, W_up, ptr_up, cnt_up, el_up,
                                        outF, ST + 448, Nf);
    bn_f32<1><<<2048, blk, 0, stream>>>(outF, ST + 448, Nf, 1.f / Nf, gam_up, bet_up, nullptr);
}